// Round 1
// baseline (809.784 us; speedup 1.0000x reference)
//
#include <hip/hip_runtime.h>

// CTRNN fused: T=512, B=256, I=64, H=256.
//   pre = x_t @ W_in^T + b_in + h @ W_hh^T + b_hh + noise_t
//   h   = max(0.8*h + 0.2*pre, 0)
//
// Single kernel, 256 blocks (1 per batch row, 1 per CU) x 1024 threads
// (16 waves, 4/SIMD). Structure (R4):
//  - Wave g owns k-chunk [16g,16g+16) of h AND output rows [16g,16g+16).
//    The rows it updates are exactly the h-values it consumes next step ->
//    h is wave-private (hbuf write->read same-wave, program-ordered, NO
//    barrier needed).
//  - x@W_in^T fused in: wave g also takes x-k [4g,4g+4) (16 FMAs/thread,
//    wi[4][4] regs). prex kernel + its 134MB HBM round-trip eliminated.
//  - ONE barrier/step: raw s_barrier with lgkmcnt(0)-only drain (asm with
//    memory clobber). __syncthreads() would vmcnt(0)-drain the x/noise
//    prefetches and out store every step (the m97 barrier-drain stall).
//    pbuf is double-buffered so reduce(t) reads and FMA(t+1) writes never
//    collide across the single barrier.
//  - Reduce spread over all 64 lanes: lane l sums waves {q,q+4,q+8,q+12}
//    (q=l>>4) for row 16g+(l&15), then shfl_xor 16/32. pbuf gg-stride 264
//    (264 mod 32 = 8) makes the strided reads 2-way max (free per m136).
//  - All private arrays FULLY const-indexed (R3 scratch lesson). Weights
//    64+16=80 floats/thread (R2 AGPR-overflow lesson: stay well under 128).

#define T_STEPS 512
#define BATCH   256
#define INSZ    64
#define HID     256
#define ALPHA_F 0.2f
#define OMA_F   0.8f

__global__ __launch_bounds__(1024, 4)
void ctrnn_fused(const float* __restrict__ x,       // [T, B, I]
                 const float* __restrict__ hidden,  // [B, H]
                 const float* __restrict__ noise,   // [T, H]
                 const float* __restrict__ W_in,    // [H, I]
                 const float* __restrict__ b_in,    // [H]
                 const float* __restrict__ W_hh,    // [H, H]
                 const float* __restrict__ b_hh,    // [H]
                 float* __restrict__ out)           // [T,B,H] ++ [B,H]
{
    const int tid  = threadIdx.x;
    const int lane = tid & 63;
    const int g    = tid >> 6;          // wave 0..15: hh-k [16g,16g+16), x-k [4g,4g+4)
    const int b    = blockIdx.x;

    __shared__ __align__(16) float xbuf[2][INSZ];
    __shared__ __align__(16) float hbuf[HID];
    __shared__ __align__(16) float pbuf[2][16 * 264]; // [buf][gg*264 + m*64 + jj]

    // ---- weights: W_hh 4 rows x 16 k, W_in 4 rows x 4 k (80 regs) ----
    float w[4][16];
#pragma unroll
    for (int m = 0; m < 4; ++m) {
        const float* wr = &W_hh[(lane + 64 * m) * HID + 16 * g];
#pragma unroll
        for (int c = 0; c < 4; ++c) {
            float4 v = *reinterpret_cast<const float4*>(&wr[4 * c]);
            w[m][4*c]   = v.x; w[m][4*c+1] = v.y;
            w[m][4*c+2] = v.z; w[m][4*c+3] = v.w;
        }
    }
    float wi[4][4];
#pragma unroll
    for (int m = 0; m < 4; ++m) {
        float4 v = *reinterpret_cast<const float4*>(
            &W_in[(lane + 64 * m) * INSZ + 4 * g]);
        wi[m][0] = v.x; wi[m][1] = v.y; wi[m][2] = v.z; wi[m][3] = v.w;
    }

    // Row this lane reduces/updates (replicated across the 4 q-groups).
    const int rrow = 16 * g + (lane & 15);
    const float biasl = b_in[rrow] + b_hh[rrow];
    float hj  = hidden[b * HID + rrow];
    float nn0 = noise[rrow];              // noise(t=0)
    float nn1 = noise[HID + rrow];        // noise(t=1)

    // x staging: t=0 -> xbuf[0]; t=1 -> xr (2-deep pipeline).
    float4 xr = make_float4(0.f, 0.f, 0.f, 0.f);
    if (g == 0 && lane < 16) {
        *reinterpret_cast<float4*>(&xbuf[0][4 * lane]) =
            *reinterpret_cast<const float4*>(&x[(size_t)b * INSZ + 4 * lane]);
        xr = *reinterpret_cast<const float4*>(
            &x[((size_t)BATCH + b) * INSZ + 4 * lane]);
    }
    if (lane < 16) hbuf[rrow] = hj;       // wave-private h chunk init
    __syncthreads();                      // xbuf[0] visible (full drain OK once)

    const int redoff = ((g >> 2) << 6) + ((g & 3) << 4) + (lane & 15);
    const int q = lane >> 4;

#pragma unroll 1
    for (int t = 0; t < T_STEPS; ++t) {
        const int cur = t & 1;

        // ---- prefetch issue (stays in flight across the barrier) ----
        float nn2 = 0.f;
        if (t + 2 < T_STEPS) nn2 = noise[(t + 2) * HID + rrow];
        if (g == 0 && lane < 16) {
            *reinterpret_cast<float4*>(&xbuf[cur ^ 1][4 * lane]) = xr; // x(t+1)
            if (t + 2 < T_STEPS)
                xr = *reinterpret_cast<const float4*>(
                    &x[((size_t)(t + 2) * BATCH + b) * INSZ + 4 * lane]);
        }

        // ---- FMA phase: h chunk is wave-private (written last step) ----
        const float4 h0 = *reinterpret_cast<const float4*>(&hbuf[16 * g]);
        const float4 h1 = *reinterpret_cast<const float4*>(&hbuf[16 * g + 4]);
        const float4 h2 = *reinterpret_cast<const float4*>(&hbuf[16 * g + 8]);
        const float4 h3 = *reinterpret_cast<const float4*>(&hbuf[16 * g + 12]);
        const float4 xv = *reinterpret_cast<const float4*>(&xbuf[cur][4 * g]);

        float accs[4];
#pragma unroll
        for (int m = 0; m < 4; ++m) {     // FULL unroll: const indices only
            float a  = w[m][0] * h0.x;
            float bq = w[m][1] * h0.y;
            float cc = wi[m][0] * xv.x;
            float dd = wi[m][1] * xv.y;
            a  = fmaf(w[m][2],  h0.z, a);  bq = fmaf(w[m][3],  h0.w, bq);
            cc = fmaf(wi[m][2], xv.z, cc); dd = fmaf(wi[m][3], xv.w, dd);
            a  = fmaf(w[m][4],  h1.x, a);  bq = fmaf(w[m][5],  h1.y, bq);
            a  = fmaf(w[m][6],  h1.z, a);  bq = fmaf(w[m][7],  h1.w, bq);
            a  = fmaf(w[m][8],  h2.x, a);  bq = fmaf(w[m][9],  h2.y, bq);
            a  = fmaf(w[m][10], h2.z, a);  bq = fmaf(w[m][11], h2.w, bq);
            a  = fmaf(w[m][12], h3.x, a);  bq = fmaf(w[m][13], h3.y, bq);
            a  = fmaf(w[m][14], h3.z, a);  bq = fmaf(w[m][15], h3.w, bq);
            accs[m] = (a + bq) + (cc + dd);
        }

        // Partials: [g*264 + m*64 + jj], lanes stride 1 -> conflict-free.
        float* pb = &pbuf[cur][g * 264 + lane];
        pb[0]   = accs[0];
        pb[64]  = accs[1];
        pb[128] = accs[2];
        pb[192] = accs[3];

        // ONE barrier: drain LDS only; global prefetches/stores keep flying.
        asm volatile("s_waitcnt lgkmcnt(0)\n\ts_barrier" ::: "memory");

        // ---- reduce (all 64 lanes): waves {q, q+4, q+8, q+12} for rrow ----
        // addr = (q+4c)*264 + (g>>2)*64 + (g&3)*16 + (l&15); 264%32=8 ->
        // banks (q*8 + l&15 + const)%32: exactly 2 lanes/bank -> free.
        const float* pr = &pbuf[cur][q * 264 + redoff];
        float s = (pr[0] + pr[1056]) + (pr[2112] + pr[3168]);
        s += __shfl_xor(s, 16);
        s += __shfl_xor(s, 32);

        const float pre = s + biasl + nn0;
        hj = fmaxf(fmaf(OMA_F, hj, ALPHA_F * pre), 0.f);
        if (lane < 16) {
            out[((size_t)t * BATCH + b) * HID + rrow] = hj;  // fire-and-forget
            hbuf[rrow] = hj;   // wave-private publish; read next iter, same wave
        }
        nn0 = nn1; nn1 = nn2;
    }

    if (lane < 16) {
        out[(size_t)T_STEPS * BATCH * HID + (size_t)b * HID + rrow] = hj;
    }
}

extern "C" void kernel_launch(void* const* d_in, const int* in_sizes, int n_in,
                              void* d_out, int out_size, void* d_ws, size_t ws_size,
                              hipStream_t stream) {
    const float* x      = (const float*)d_in[0];
    const float* hidden = (const float*)d_in[1];
    const float* noise  = (const float*)d_in[2];
    const float* W_in   = (const float*)d_in[3];
    const float* b_in   = (const float*)d_in[4];
    const float* W_hh   = (const float*)d_in[5];
    const float* b_hh   = (const float*)d_in[6];
    float* out = (float*)d_out;

    hipLaunchKernelGGL(ctrnn_fused, dim3(BATCH), dim3(1024), 0, stream,
                       x, hidden, noise, W_in, b_in, W_hh, b_hh, out);
}